// Round 1
// baseline (1493.621 us; speedup 1.0000x reference)
//
#include <hip/hip_runtime.h>
#include <stdint.h>
#include <math.h>

#define N_NODES 100000
#define N_EDGES 1600000
#define IN_DIM 128
#define HID 256
#define N_CLS 40

// ---------------------------------------------------------------------------
// Index-format detection: edge_index is int64 in the reference, but may arrive
// as int32 (JAX x64 disabled / harness conversion). For non-negative values
// < 2^31 stored little-endian int64, every odd 32-bit word is 0. For int32
// data the odd words are random node ids. OR-reduce odd words -> flag.
// ---------------------------------------------------------------------------
__global__ __launch_bounds__(256) void k_detect(const unsigned int* __restrict__ ew,
                                                int* __restrict__ flag) {
  __shared__ unsigned int sh[256];
  unsigned int v = 0;
  for (int i = threadIdx.x; i < 4096; i += 256) v |= ew[2 * i + 1];
  sh[threadIdx.x] = v;
  __syncthreads();
  for (int s = 128; s > 0; s >>= 1) {
    if (threadIdx.x < s) sh[threadIdx.x] |= sh[threadIdx.x + s];
    __syncthreads();
  }
  if (threadIdx.x == 0) flag[0] = (sh[0] == 0u) ? 1 : 0;  // 1 => int64
}

__global__ __launch_bounds__(256) void k_init_deg(int* __restrict__ deg) {
  int i = blockIdx.x * 256 + threadIdx.x;
  if (i < N_NODES) deg[i] = 0;
}

// Convert edge_index (either dtype) to int32 src/dst, count in-degrees.
__global__ __launch_bounds__(256) void k_convert(const void* __restrict__ eidx,
                                                 const int* __restrict__ flag,
                                                 int* __restrict__ src,
                                                 int* __restrict__ dst,
                                                 int* __restrict__ deg) {
  int k = blockIdx.x * 256 + threadIdx.x;
  if (k >= 2 * N_EDGES) return;
  int vi;
  if (flag[0]) vi = (int)((const long long*)eidx)[k];
  else         vi = ((const int*)eidx)[k];
  if (k < N_EDGES) {
    src[k] = vi;
  } else {
    dst[k - N_EDGES] = vi;
    atomicAdd(&deg[vi], 1);
  }
}

__global__ __launch_bounds__(256) void k_dinv(const int* __restrict__ deg,
                                              float* __restrict__ dinv) {
  int i = blockIdx.x * 256 + threadIdx.x;
  if (i >= N_NODES) return;
  dinv[i] = rsqrtf((float)(deg[i] + 1));  // +1 self-loop; always > 0
}

// ---- exclusive prefix sum over deg (in-edge counts) -> CSR row_start ----
__global__ __launch_bounds__(256) void k_scan1(const int* __restrict__ deg,
                                               int* __restrict__ incl,
                                               int* __restrict__ bsums) {
  __shared__ int sh[256];
  int i = blockIdx.x * 256 + threadIdx.x;
  int v = (i < N_NODES) ? deg[i] : 0;
  sh[threadIdx.x] = v;
  __syncthreads();
  for (int off = 1; off < 256; off <<= 1) {
    int t = (threadIdx.x >= (unsigned)off) ? sh[threadIdx.x - off] : 0;
    __syncthreads();
    sh[threadIdx.x] += t;
    __syncthreads();
  }
  if (i < N_NODES) incl[i] = sh[threadIdx.x];
  if (threadIdx.x == 255) bsums[blockIdx.x] = sh[255];
}

__global__ __launch_bounds__(512) void k_scan2(int* __restrict__ bsums, int nb) {
  __shared__ int sh[512];
  int t = threadIdx.x;
  sh[t] = (t < nb) ? bsums[t] : 0;
  __syncthreads();
  for (int off = 1; off < 512; off <<= 1) {
    int v = (t >= off) ? sh[t - off] : 0;
    __syncthreads();
    sh[t] += v;
    __syncthreads();
  }
  if (t < nb) bsums[t] = (t == 0) ? 0 : sh[t - 1];  // exclusive
}

__global__ __launch_bounds__(256) void k_scan3(const int* __restrict__ deg,
                                               const int* __restrict__ incl,
                                               const int* __restrict__ bsums,
                                               int* __restrict__ row_start,
                                               int* __restrict__ cursor) {
  int i = blockIdx.x * 256 + threadIdx.x;
  if (i >= N_NODES) return;
  int rs = incl[i] - deg[i] + bsums[blockIdx.x];
  row_start[i] = rs;
  cursor[i] = rs;
  if (i == 0) row_start[N_NODES] = N_EDGES;
}

// Counting-sort edges by dst into CSR; weight = dinv[src]*dinv[dst].
__global__ __launch_bounds__(256) void k_fill(const int* __restrict__ src,
                                              const int* __restrict__ dst,
                                              const float* __restrict__ dinv,
                                              int* __restrict__ cursor,
                                              int* __restrict__ csr_src,
                                              float* __restrict__ csr_w) {
  int e = blockIdx.x * 256 + threadIdx.x;
  if (e >= N_EDGES) return;
  int s = src[e], d = dst[e];
  int p = atomicAdd(&cursor[d], 1);
  csr_src[p] = s;
  csr_w[p] = dinv[s] * dinv[d];
}

// ---- gather-based aggregation: one wave per node, lanes split features ----
template <int F, int VPL>  // F = VPL * 64
__global__ __launch_bounds__(256) void k_agg(const float* __restrict__ in,
                                             float* __restrict__ out,
                                             const float* __restrict__ dinv,
                                             const int* __restrict__ row_start,
                                             const int* __restrict__ csr_src,
                                             const float* __restrict__ csr_w) {
  int wave = threadIdx.x >> 6;
  int lane = threadIdx.x & 63;
  int node = blockIdx.x * (blockDim.x >> 6) + wave;
  if (node >= N_NODES) return;
  float d = dinv[node];
  float d2 = d * d;
  float acc[VPL];
  const float* row = in + (size_t)node * F + lane * VPL;
#pragma unroll
  for (int c = 0; c < VPL; c++) acc[c] = row[c] * d2;  // self-loop
  int e0 = row_start[node], e1 = row_start[node + 1];
  for (int e = e0; e < e1; e++) {
    int s = csr_src[e];
    float w = csr_w[e];
    const float* r = in + (size_t)s * F + lane * VPL;
#pragma unroll
    for (int c = 0; c < VPL; c++) acc[c] += r[c] * w;
  }
  float* o = out + (size_t)node * F + lane * VPL;
#pragma unroll
  for (int c = 0; c < VPL; c++) o[c] = acc[c];
}

// 40-wide aggregation + bias (layer 3, post-GEMM)
__global__ __launch_bounds__(256) void k_agg40(const float* __restrict__ in,
                                               float* __restrict__ out,
                                               const float* __restrict__ dinv,
                                               const int* __restrict__ row_start,
                                               const int* __restrict__ csr_src,
                                               const float* __restrict__ csr_w,
                                               const float* __restrict__ bias) {
  int wave = threadIdx.x >> 6;
  int lane = threadIdx.x & 63;
  int node = blockIdx.x * (blockDim.x >> 6) + wave;
  if (node >= N_NODES) return;
  float d = dinv[node];
  float acc = 0.f;
  if (lane < N_CLS) acc = in[(size_t)node * N_CLS + lane] * d * d;
  int e0 = row_start[node], e1 = row_start[node + 1];
  for (int e = e0; e < e1; e++) {
    int s = csr_src[e];
    float w = csr_w[e];
    if (lane < N_CLS) acc += in[(size_t)s * N_CLS + lane] * w;
  }
  if (lane < N_CLS) out[(size_t)node * N_CLS + lane] = acc + bias[lane];
}

// ---- fp32 tiled GEMM: C[M,Nc] = A[M,K] @ B[K,Nc] (+bias)(+relu) ----
__global__ __launch_bounds__(256) void k_gemm(const float* __restrict__ A,
                                              const float* __restrict__ B,
                                              const float* __restrict__ bias,
                                              float* __restrict__ C,
                                              int M, int K, int Nc, int relu) {
  __shared__ float As[16][65];
  __shared__ float Bs[16][65];
  int tid = threadIdx.x;
  int tx = tid & 15, ty = tid >> 4;
  int row0 = blockIdx.x * 64, col0 = blockIdx.y * 64;
  float acc[4][4] = {};
  for (int k0 = 0; k0 < K; k0 += 16) {
    for (int i = tid; i < 64 * 16; i += 256) {
      int r = i >> 4, c = i & 15;
      int gr = row0 + r;
      As[c][r] = (gr < M) ? A[(size_t)gr * K + k0 + c] : 0.f;
    }
    for (int i = tid; i < 16 * 64; i += 256) {
      int r = i >> 6, c = i & 63;
      int gc = col0 + c;
      Bs[r][c] = (gc < Nc) ? B[(size_t)(k0 + r) * Nc + gc] : 0.f;
    }
    __syncthreads();
#pragma unroll
    for (int k = 0; k < 16; k++) {
      float a[4], b[4];
#pragma unroll
      for (int i = 0; i < 4; i++) a[i] = As[k][ty * 4 + i];
#pragma unroll
      for (int j = 0; j < 4; j++) b[j] = Bs[k][tx * 4 + j];
#pragma unroll
      for (int i = 0; i < 4; i++)
#pragma unroll
        for (int j = 0; j < 4; j++) acc[i][j] += a[i] * b[j];
    }
    __syncthreads();
  }
#pragma unroll
  for (int i = 0; i < 4; i++) {
    int gr = row0 + ty * 4 + i;
    if (gr >= M) continue;
#pragma unroll
    for (int j = 0; j < 4; j++) {
      int gc = col0 + tx * 4 + j;
      if (gc >= Nc) continue;
      float v = acc[i][j] + (bias ? bias[gc] : 0.f);
      if (relu) v = fmaxf(v, 0.f);
      C[(size_t)gr * Nc + gc] = v;
    }
  }
}

__global__ __launch_bounds__(256) void k_logsoftmax(float* __restrict__ out) {
  int wave = threadIdx.x >> 6;
  int lane = threadIdx.x & 63;
  int node = blockIdx.x * (blockDim.x >> 6) + wave;
  if (node >= N_NODES) return;
  float v = (lane < N_CLS) ? out[(size_t)node * N_CLS + lane] : -INFINITY;
  float m = v;
  for (int off = 32; off; off >>= 1) m = fmaxf(m, __shfl_down(m, off));
  m = __shfl(m, 0);
  float e = (lane < N_CLS) ? expf(v - m) : 0.f;
  float s = e;
  for (int off = 32; off; off >>= 1) s += __shfl_down(s, off);
  s = __shfl(s, 0);
  float lse = m + logf(s);
  if (lane < N_CLS) out[(size_t)node * N_CLS + lane] = v - lse;
}

// ---------------------------------------------------------------------------
extern "C" void kernel_launch(void* const* d_in, const int* in_sizes, int n_in,
                              void* d_out, int out_size, void* d_ws, size_t ws_size,
                              hipStream_t stream) {
  const float* x  = (const float*)d_in[0];
  const void*  ei = d_in[1];
  const float* W1 = (const float*)d_in[2];
  const float* b1 = (const float*)d_in[3];
  const float* W2 = (const float*)d_in[4];
  const float* b2 = (const float*)d_in[5];
  const float* W3 = (const float*)d_in[6];
  const float* b3 = (const float*)d_in[7];
  float* out = (float*)d_out;

  // workspace carve-out (256B aligned regions)
  char* w = (char*)d_ws;
  auto alloc = [&](size_t bytes) {
    char* p = w;
    w += (bytes + 255) & ~(size_t)255;
    return p;
  };
  int*   flag      = (int*)alloc(64);
  int*   src       = (int*)alloc((size_t)N_EDGES * 4);
  int*   dst       = (int*)alloc((size_t)N_EDGES * 4);
  int*   deg       = (int*)alloc((size_t)N_NODES * 4);
  float* dinv      = (float*)alloc((size_t)N_NODES * 4);
  int*   incl      = (int*)alloc((size_t)N_NODES * 4);
  int*   cursor    = (int*)alloc((size_t)N_NODES * 4);
  int*   row_start = (int*)alloc(((size_t)N_NODES + 1) * 4);
  int*   bsums     = (int*)alloc(2048);
  int*   csr_src   = (int*)alloc((size_t)N_EDGES * 4);
  float* csr_w     = (float*)alloc((size_t)N_EDGES * 4);
  float* bufA      = (float*)alloc((size_t)N_NODES * HID * 4);
  float* bufB      = (float*)alloc((size_t)N_NODES * HID * 4);

  const int nb_nodes = (N_NODES + 255) / 256;            // 391
  const int nb_conv  = (2 * N_EDGES + 255) / 256;        // 12500
  const int nb_edges = (N_EDGES + 255) / 256;            // 6250
  const int nb_wave4 = (N_NODES + 3) / 4;                // 25000 (4 waves/block)
  const int gm       = (N_NODES + 63) / 64;              // 1563

  // graph preprocessing
  k_detect<<<1, 256, 0, stream>>>((const unsigned int*)ei, flag);
  k_init_deg<<<nb_nodes, 256, 0, stream>>>(deg);
  k_convert<<<nb_conv, 256, 0, stream>>>(ei, flag, src, dst, deg);
  k_dinv<<<nb_nodes, 256, 0, stream>>>(deg, dinv);
  k_scan1<<<nb_nodes, 256, 0, stream>>>(deg, incl, bsums);
  k_scan2<<<1, 512, 0, stream>>>(bsums, nb_nodes);
  k_scan3<<<nb_nodes, 256, 0, stream>>>(deg, incl, bsums, row_start, cursor);
  k_fill<<<nb_edges, 256, 0, stream>>>(src, dst, dinv, cursor, csr_src, csr_w);

  // layer 1: agg(x) @ W1 + b1, relu   (aggregate 128-dim first — linearity)
  k_agg<IN_DIM, 2><<<nb_wave4, 256, 0, stream>>>(x, bufA, dinv, row_start, csr_src, csr_w);
  k_gemm<<<dim3(gm, HID / 64), 256, 0, stream>>>(bufA, W1, b1, bufB, N_NODES, IN_DIM, HID, 1);

  // layer 2: agg(g1) @ W2 + b2, relu
  k_agg<HID, 4><<<nb_wave4, 256, 0, stream>>>(bufB, bufA, dinv, row_start, csr_src, csr_w);
  k_gemm<<<dim3(gm, HID / 64), 256, 0, stream>>>(bufA, W2, b2, bufB, N_NODES, HID, HID, 1);

  // layer 3: agg(g2 @ W3) + b3, then log_softmax
  k_gemm<<<dim3(gm, 1), 256, 0, stream>>>(bufB, W3, nullptr, bufA, N_NODES, HID, N_CLS, 0);
  k_agg40<<<nb_wave4, 256, 0, stream>>>(bufA, out, dinv, row_start, csr_src, csr_w, b3);
  k_logsoftmax<<<nb_wave4, 256, 0, stream>>>(out);
}

// Round 2
// 957.869 us; speedup vs baseline: 1.5593x; 1.5593x over previous
//
#include <hip/hip_runtime.h>
#include <stdint.h>
#include <math.h>

#define N_NODES 100000
#define N_EDGES 1600000
#define IN_DIM 128
#define HID 256
#define N_CLS 40
#define M_TOT N_NODES

typedef __attribute__((ext_vector_type(8))) short short8;
typedef __attribute__((ext_vector_type(4))) float f32x4;

__device__ __forceinline__ unsigned short f2bf(float f) {
  unsigned b = __float_as_uint(f);
  b += 0x7fffu + ((b >> 16) & 1u);   // round-to-nearest-even
  return (unsigned short)(b >> 16);
}
__device__ __forceinline__ float bf2f(unsigned short h) {
  return __uint_as_float(((unsigned)h) << 16);
}

// ---------------------------------------------------------------------------
// edge_index dtype detection (int64 vs int32) — odd 32-bit words all zero => i64
// ---------------------------------------------------------------------------
__global__ __launch_bounds__(256) void k_detect(const unsigned int* __restrict__ ew,
                                                int* __restrict__ flag) {
  __shared__ unsigned int sh[256];
  unsigned int v = 0;
  for (int i = threadIdx.x; i < 4096; i += 256) v |= ew[2 * i + 1];
  sh[threadIdx.x] = v;
  __syncthreads();
  for (int s = 128; s > 0; s >>= 1) {
    if (threadIdx.x < s) sh[threadIdx.x] |= sh[threadIdx.x + s];
    __syncthreads();
  }
  if (threadIdx.x == 0) flag[0] = (sh[0] == 0u) ? 1 : 0;
}

__global__ __launch_bounds__(256) void k_init_deg(int* __restrict__ deg) {
  int i = blockIdx.x * 256 + threadIdx.x;
  if (i < N_NODES) deg[i] = 0;
}

__global__ __launch_bounds__(256) void k_convert(const void* __restrict__ eidx,
                                                 const int* __restrict__ flag,
                                                 int* __restrict__ src,
                                                 int* __restrict__ dst,
                                                 int* __restrict__ deg) {
  int k = blockIdx.x * 256 + threadIdx.x;
  if (k >= 2 * N_EDGES) return;
  int vi;
  if (flag[0]) vi = (int)((const long long*)eidx)[k];
  else         vi = ((const int*)eidx)[k];
  if (k < N_EDGES) {
    src[k] = vi;
  } else {
    dst[k - N_EDGES] = vi;
    atomicAdd(&deg[vi], 1);
  }
}

__global__ __launch_bounds__(256) void k_dinv(const int* __restrict__ deg,
                                              float* __restrict__ dinv) {
  int i = blockIdx.x * 256 + threadIdx.x;
  if (i >= N_NODES) return;
  dinv[i] = rsqrtf((float)(deg[i] + 1));
}

__global__ __launch_bounds__(256) void k_scan1(const int* __restrict__ deg,
                                               int* __restrict__ incl,
                                               int* __restrict__ bsums) {
  __shared__ int sh[256];
  int i = blockIdx.x * 256 + threadIdx.x;
  int v = (i < N_NODES) ? deg[i] : 0;
  sh[threadIdx.x] = v;
  __syncthreads();
  for (int off = 1; off < 256; off <<= 1) {
    int t = (threadIdx.x >= (unsigned)off) ? sh[threadIdx.x - off] : 0;
    __syncthreads();
    sh[threadIdx.x] += t;
    __syncthreads();
  }
  if (i < N_NODES) incl[i] = sh[threadIdx.x];
  if (threadIdx.x == 255) bsums[blockIdx.x] = sh[255];
}

__global__ __launch_bounds__(512) void k_scan2(int* __restrict__ bsums, int nb) {
  __shared__ int sh[512];
  int t = threadIdx.x;
  sh[t] = (t < nb) ? bsums[t] : 0;
  __syncthreads();
  for (int off = 1; off < 512; off <<= 1) {
    int v = (t >= off) ? sh[t - off] : 0;
    __syncthreads();
    sh[t] += v;
    __syncthreads();
  }
  if (t < nb) bsums[t] = (t == 0) ? 0 : sh[t - 1];
}

__global__ __launch_bounds__(256) void k_scan3(const int* __restrict__ deg,
                                               const int* __restrict__ incl,
                                               const int* __restrict__ bsums,
                                               int* __restrict__ row_start,
                                               int* __restrict__ cursor) {
  int i = blockIdx.x * 256 + threadIdx.x;
  if (i >= N_NODES) return;
  int rs = incl[i] - deg[i] + bsums[blockIdx.x];
  row_start[i] = rs;
  cursor[i] = rs;
  if (i == 0) row_start[N_NODES] = N_EDGES;
}

__global__ __launch_bounds__(256) void k_fill(const int* __restrict__ src,
                                              const int* __restrict__ dst,
                                              const float* __restrict__ dinv,
                                              int* __restrict__ cursor,
                                              int* __restrict__ csr_src,
                                              float* __restrict__ csr_w) {
  int e = blockIdx.x * 256 + threadIdx.x;
  if (e >= N_EDGES) return;
  int s = src[e], d = dst[e];
  int p = atomicAdd(&cursor[d], 1);
  csr_src[p] = s;
  csr_w[p] = dinv[s] * dinv[d];
}

// ---------------------------------------------------------------------------
// fp32 -> bf16 convert (x input)
// ---------------------------------------------------------------------------
__global__ __launch_bounds__(256) void k_x2bf(const float* __restrict__ x,
                                              unsigned short* __restrict__ o,
                                              int n4) {
  int i = blockIdx.x * 256 + threadIdx.x;
  if (i >= n4) return;
  const float4* xv = (const float4*)x;
  float4 v = xv[i];
  ushort4 r;
  r.x = f2bf(v.x); r.y = f2bf(v.y); r.z = f2bf(v.z); r.w = f2bf(v.w);
  ((ushort4*)o)[i] = r;
}

// ---------------------------------------------------------------------------
// weight transpose + hi/lo bf16 split:  W[K][N] -> Bh/Bl[Npad][K]
// ---------------------------------------------------------------------------
__global__ __launch_bounds__(256) void k_wsplit(const float* __restrict__ W,
                                                int K, int N, int Npad,
                                                unsigned short* __restrict__ Bh,
                                                unsigned short* __restrict__ Bl) {
  int idx = blockIdx.x * 256 + threadIdx.x;
  if (idx >= Npad * K) return;
  int n = idx / K, k = idx - n * K;
  float w = (n < N) ? W[(size_t)k * N + n] : 0.f;
  unsigned short h = f2bf(w);
  float lo = w - bf2f(h);
  Bh[idx] = h;
  Bl[idx] = f2bf(lo);
}

// ---------------------------------------------------------------------------
// gather aggregation, bf16 in / bf16 out, fp32 accumulate. One wave per node.
// ---------------------------------------------------------------------------
template <int F>  // 128 or 256
__global__ __launch_bounds__(256) void k_agg_bf16(const unsigned short* __restrict__ in,
                                                  unsigned short* __restrict__ out,
                                                  const float* __restrict__ dinv,
                                                  const int* __restrict__ row_start,
                                                  const int* __restrict__ csr_src,
                                                  const float* __restrict__ csr_w) {
  constexpr int VU = F / 128;  // uints (bf16 pairs) per lane
  int wave = threadIdx.x >> 6;
  int lane = threadIdx.x & 63;
  int node = blockIdx.x * 4 + wave;
  if (node >= N_NODES) return;
  float d = dinv[node];
  float d2 = d * d;
  const unsigned* inu = (const unsigned*)in;
  float acc[VU * 2];
  {
    const unsigned* r = inu + (size_t)node * (F / 2) + lane * VU;
#pragma unroll
    for (int c = 0; c < VU; c++) {
      unsigned u = r[c];
      acc[2 * c]     = __uint_as_float(u << 16) * d2;
      acc[2 * c + 1] = __uint_as_float(u & 0xffff0000u) * d2;
    }
  }
  int e0 = row_start[node], e1 = row_start[node + 1];
  for (int e = e0; e < e1; e++) {
    int s = csr_src[e];
    float w = csr_w[e];
    const unsigned* r = inu + (size_t)s * (F / 2) + lane * VU;
#pragma unroll
    for (int c = 0; c < VU; c++) {
      unsigned u = r[c];
      acc[2 * c]     = fmaf(__uint_as_float(u << 16), w, acc[2 * c]);
      acc[2 * c + 1] = fmaf(__uint_as_float(u & 0xffff0000u), w, acc[2 * c + 1]);
    }
  }
  unsigned* ou = (unsigned*)out + (size_t)node * (F / 2) + lane * VU;
#pragma unroll
  for (int c = 0; c < VU; c++) {
    unsigned lo = f2bf(acc[2 * c]);
    unsigned hi = f2bf(acc[2 * c + 1]);
    ou[c] = lo | (hi << 16);
  }
}

// ---------------------------------------------------------------------------
// MFMA GEMM: C[M,ldc] = A[M,K](bf16) @ (Bh+Bl)[Npad,K]^T (+bias)(+relu)
// 128x128 tile, BK=32, 4 waves in 2x2, each wave 64x64 (4x4 mfma tiles).
// Weights split hi/lo bf16 => effective fp32 weight precision.
// ---------------------------------------------------------------------------
template <bool OUTBF>
__global__ __launch_bounds__(256) void k_gemm_mfma(const unsigned short* __restrict__ A,
                                                   int lda,
                                                   const unsigned short* __restrict__ Bh,
                                                   const unsigned short* __restrict__ Bl,
                                                   const float* __restrict__ bias,
                                                   void* __restrict__ C, int ldc,
                                                   int M, int K, int relu) {
  __shared__ alignas(16) unsigned short As[128][40];
  __shared__ alignas(16) unsigned short Bhs[128][40];
  __shared__ alignas(16) unsigned short Bls[128][40];
  int tid = threadIdx.x;
  int lane = tid & 63, wv = tid >> 6;
  int wy = wv >> 1, wx = wv & 1;
  int row0 = blockIdx.x * 128, col0 = blockIdx.y * 128;

  f32x4 acc[4][4];
#pragma unroll
  for (int i = 0; i < 4; i++)
#pragma unroll
    for (int j = 0; j < 4; j++) acc[i][j] = 0.f;

  // staging indices: 512 short8 slots per tile, 256 threads x 2
  int sr0 = tid >> 2;            // rows 0..63
  int sc = (tid & 3) * 8;        // col 0,8,16,24

  for (int k0 = 0; k0 < K; k0 += 32) {
#pragma unroll
    for (int it = 0; it < 2; it++) {
      int r = sr0 + it * 64;
      int gr = row0 + r;
      short8 va = 0;
      if (gr < M) va = *(const short8*)(A + (size_t)gr * lda + k0 + sc);
      *(short8*)&As[r][sc] = va;
      short8 vh = *(const short8*)(Bh + (size_t)(col0 + r) * K + k0 + sc);
      short8 vl = *(const short8*)(Bl + (size_t)(col0 + r) * K + k0 + sc);
      *(short8*)&Bhs[r][sc] = vh;
      *(short8*)&Bls[r][sc] = vl;
    }
    __syncthreads();

    int ar = wy * 64 + (lane & 15);
    int br = wx * 64 + (lane & 15);
    int kk = (lane >> 4) * 8;
    short8 a[4], bh[4], bl[4];
#pragma unroll
    for (int mi = 0; mi < 4; mi++) a[mi] = *(const short8*)&As[ar + mi * 16][kk];
#pragma unroll
    for (int ni = 0; ni < 4; ni++) {
      bh[ni] = *(const short8*)&Bhs[br + ni * 16][kk];
      bl[ni] = *(const short8*)&Bls[br + ni * 16][kk];
    }
#pragma unroll
    for (int mi = 0; mi < 4; mi++)
#pragma unroll
      for (int ni = 0; ni < 4; ni++) {
        acc[mi][ni] = __builtin_amdgcn_mfma_f32_16x16x32_bf16(a[mi], bh[ni], acc[mi][ni], 0, 0, 0);
        acc[mi][ni] = __builtin_amdgcn_mfma_f32_16x16x32_bf16(a[mi], bl[ni], acc[mi][ni], 0, 0, 0);
      }
    __syncthreads();
  }

  // epilogue: C/D layout col=lane&15, row=(lane>>4)*4+r
  int mbase = row0 + wy * 64;
  int nbase = col0 + wx * 64;
#pragma unroll
  for (int ni = 0; ni < 4; ni++) {
    int gc = nbase + ni * 16 + (lane & 15);
    float bz = bias ? bias[gc] : 0.f;
#pragma unroll
    for (int mi = 0; mi < 4; mi++) {
      f32x4 v = acc[mi][ni];
#pragma unroll
      for (int r = 0; r < 4; r++) {
        int gr = mbase + mi * 16 + (lane >> 4) * 4 + r;
        if (gr < M) {
          float o = v[r] + bz;
          if (relu) o = fmaxf(o, 0.f);
          if (OUTBF) ((unsigned short*)C)[(size_t)gr * ldc + gc] = f2bf(o);
          else       ((float*)C)[(size_t)gr * ldc + gc] = o;
        }
      }
    }
  }
}

// ---------------------------------------------------------------------------
// layer-3 aggregation (40 classes, input fp32 stride 128) + bias + log_softmax
// ---------------------------------------------------------------------------
__global__ __launch_bounds__(256) void k_agg40_lsm(const float* __restrict__ in,
                                                   float* __restrict__ out,
                                                   const float* __restrict__ dinv,
                                                   const int* __restrict__ row_start,
                                                   const int* __restrict__ csr_src,
                                                   const float* __restrict__ csr_w,
                                                   const float* __restrict__ bias) {
  int wave = threadIdx.x >> 6;
  int lane = threadIdx.x & 63;
  int node = blockIdx.x * 4 + wave;
  if (node >= N_NODES) return;
  float d = dinv[node];
  bool act = lane < N_CLS;
  float acc = 0.f;
  if (act) acc = in[(size_t)node * 128 + lane] * d * d;
  int e0 = row_start[node], e1 = row_start[node + 1];
  for (int e = e0; e < e1; e++) {
    int s = csr_src[e];
    float w = csr_w[e];
    if (act) acc = fmaf(in[(size_t)s * 128 + lane], w, acc);
  }
  float v = act ? acc + bias[lane] : -INFINITY;
  float m = v;
  for (int off = 32; off; off >>= 1) m = fmaxf(m, __shfl_down(m, off));
  m = __shfl(m, 0);
  float e = act ? expf(v - m) : 0.f;
  float s = e;
  for (int off = 32; off; off >>= 1) s += __shfl_down(s, off);
  s = __shfl(s, 0);
  float lse = m + logf(s);
  if (act) out[(size_t)node * N_CLS + lane] = v - lse;
}

// ---------------------------------------------------------------------------
extern "C" void kernel_launch(void* const* d_in, const int* in_sizes, int n_in,
                              void* d_out, int out_size, void* d_ws, size_t ws_size,
                              hipStream_t stream) {
  const float* x  = (const float*)d_in[0];
  const void*  ei = d_in[1];
  const float* W1 = (const float*)d_in[2];
  const float* b1 = (const float*)d_in[3];
  const float* W2 = (const float*)d_in[4];
  const float* b2 = (const float*)d_in[5];
  const float* W3 = (const float*)d_in[6];
  const float* b3 = (const float*)d_in[7];
  float* out = (float*)d_out;

  char* w = (char*)d_ws;
  auto alloc = [&](size_t bytes) {
    char* p = w;
    w += (bytes + 255) & ~(size_t)255;
    return p;
  };
  int*   flag      = (int*)alloc(64);
  int*   src       = (int*)alloc((size_t)N_EDGES * 4);
  int*   dst       = (int*)alloc((size_t)N_EDGES * 4);
  int*   deg       = (int*)alloc((size_t)N_NODES * 4);
  float* dinv      = (float*)alloc((size_t)N_NODES * 4);
  int*   incl      = (int*)alloc((size_t)N_NODES * 4);
  int*   cursor    = (int*)alloc((size_t)N_NODES * 4);
  int*   row_start = (int*)alloc(((size_t)N_NODES + 1) * 4);
  int*   bsums     = (int*)alloc(2048);
  int*   csr_src   = (int*)alloc((size_t)N_EDGES * 4);
  float* csr_w     = (float*)alloc((size_t)N_EDGES * 4);
  unsigned short* Wt1h = (unsigned short*)alloc((size_t)HID * IN_DIM * 2);
  unsigned short* Wt1l = (unsigned short*)alloc((size_t)HID * IN_DIM * 2);
  unsigned short* Wt2h = (unsigned short*)alloc((size_t)HID * HID * 2);
  unsigned short* Wt2l = (unsigned short*)alloc((size_t)HID * HID * 2);
  unsigned short* Wt3h = (unsigned short*)alloc((size_t)128 * HID * 2);
  unsigned short* Wt3l = (unsigned short*)alloc((size_t)128 * HID * 2);
  char* B0 = alloc((size_t)N_NODES * 128 * 4);  // 51.2 MB
  char* B1 = alloc((size_t)N_NODES * HID * 2);  // 51.2 MB

  unsigned short* xb    = (unsigned short*)B0;                    // [N,128] bf16
  unsigned short* aggX  = (unsigned short*)B0 + (size_t)N_NODES * 128;
  unsigned short* h1    = (unsigned short*)B1;                    // [N,256] bf16
  unsigned short* aggH1 = (unsigned short*)B0;                    // [N,256] bf16
  unsigned short* h2    = (unsigned short*)B1;                    // [N,256] bf16
  float*          C3    = (float*)B0;                             // [N,128] f32

  const int nb_nodes = (N_NODES + 255) / 256;
  const int nb_conv  = (2 * N_EDGES + 255) / 256;
  const int nb_edges = (N_EDGES + 255) / 256;
  const int nb_wave4 = (N_NODES + 3) / 4;
  const int gm       = (N_NODES + 127) / 128;  // 782

  // graph preprocessing
  k_detect<<<1, 256, 0, stream>>>((const unsigned int*)ei, flag);
  k_init_deg<<<nb_nodes, 256, 0, stream>>>(deg);
  k_convert<<<nb_conv, 256, 0, stream>>>(ei, flag, src, dst, deg);
  k_dinv<<<nb_nodes, 256, 0, stream>>>(deg, dinv);
  k_scan1<<<nb_nodes, 256, 0, stream>>>(deg, incl, bsums);
  k_scan2<<<1, 512, 0, stream>>>(bsums, nb_nodes);
  k_scan3<<<nb_nodes, 256, 0, stream>>>(deg, incl, bsums, row_start, cursor);
  k_fill<<<nb_edges, 256, 0, stream>>>(src, dst, dinv, cursor, csr_src, csr_w);

  // weight prep + x->bf16
  k_x2bf<<<(N_NODES * IN_DIM / 4 + 255) / 256, 256, 0, stream>>>(x, xb, N_NODES * IN_DIM / 4);
  k_wsplit<<<(HID * IN_DIM + 255) / 256, 256, 0, stream>>>(W1, IN_DIM, HID, HID, Wt1h, Wt1l);
  k_wsplit<<<(HID * HID + 255) / 256, 256, 0, stream>>>(W2, HID, HID, HID, Wt2h, Wt2l);
  k_wsplit<<<(128 * HID + 255) / 256, 256, 0, stream>>>(W3, HID, N_CLS, 128, Wt3h, Wt3l);

  // layer 1: agg(x) @ W1 + b1, relu
  k_agg_bf16<IN_DIM><<<nb_wave4, 256, 0, stream>>>(xb, aggX, dinv, row_start, csr_src, csr_w);
  k_gemm_mfma<true><<<dim3(gm, HID / 128), 256, 0, stream>>>(aggX, IN_DIM, Wt1h, Wt1l, b1,
                                                             h1, HID, M_TOT, IN_DIM, 1);
  // layer 2: agg(h1) @ W2 + b2, relu
  k_agg_bf16<HID><<<nb_wave4, 256, 0, stream>>>(h1, aggH1, dinv, row_start, csr_src, csr_w);
  k_gemm_mfma<true><<<dim3(gm, HID / 128), 256, 0, stream>>>(aggH1, HID, Wt2h, Wt2l, b2,
                                                             h2, HID, M_TOT, HID, 1);
  // layer 3: agg(h2 @ W3) + b3, log_softmax  (N padded to 128, fp32 out)
  k_gemm_mfma<false><<<dim3(gm, 1), 256, 0, stream>>>(h2, HID, Wt3h, Wt3l, nullptr,
                                                      C3, 128, M_TOT, HID, 0);
  k_agg40_lsm<<<nb_wave4, 256, 0, stream>>>(C3, out, dinv, row_start, csr_src, csr_w, b3);
}

// Round 3
// 788.526 us; speedup vs baseline: 1.8942x; 1.2148x over previous
//
#include <hip/hip_runtime.h>
#include <stdint.h>
#include <math.h>

#define N_NODES 100000
#define N_EDGES 1600000
#define IN_DIM 128
#define HID 256
#define N_CLS 40

typedef __attribute__((ext_vector_type(8))) short short8;
typedef __attribute__((ext_vector_type(4))) float f32x4;

__device__ __forceinline__ unsigned short f2bf(float f) {
  unsigned b = __float_as_uint(f);
  b += 0x7fffu + ((b >> 16) & 1u);   // round-to-nearest-even
  return (unsigned short)(b >> 16);
}
__device__ __forceinline__ float bflo(unsigned u) { return __uint_as_float(u << 16); }
__device__ __forceinline__ float bfhi(unsigned u) { return __uint_as_float(u & 0xffff0000u); }

// ---------------------------------------------------------------------------
// zero deg; block 0 also detects edge_index dtype (int64 vs int32):
// odd 32-bit words of first 4096 entries all zero => little-endian int64.
// ---------------------------------------------------------------------------
__global__ __launch_bounds__(256) void k_pre0(const unsigned int* __restrict__ ew,
                                              int* __restrict__ flag,
                                              int* __restrict__ deg) {
  int i = blockIdx.x * 256 + threadIdx.x;
  if (i < N_NODES) deg[i] = 0;
  if (blockIdx.x == 0) {
    __shared__ unsigned int sh[256];
    unsigned int v = 0;
    for (int k = threadIdx.x; k < 4096; k += 256) v |= ew[2 * k + 1];
    sh[threadIdx.x] = v;
    __syncthreads();
    for (int s = 128; s > 0; s >>= 1) {
      if (threadIdx.x < s) sh[threadIdx.x] |= sh[threadIdx.x + s];
      __syncthreads();
    }
    if (threadIdx.x == 0) flag[0] = (sh[0] == 0u) ? 1 : 0;
  }
}

__global__ __launch_bounds__(256) void k_convert(const void* __restrict__ eidx,
                                                 const int* __restrict__ flag,
                                                 int* __restrict__ src,
                                                 int* __restrict__ dst,
                                                 int* __restrict__ deg) {
  int k = blockIdx.x * 256 + threadIdx.x;
  if (k >= 2 * N_EDGES) return;
  int vi;
  if (flag[0]) vi = (int)((const long long*)eidx)[k];
  else         vi = ((const int*)eidx)[k];
  if (k < N_EDGES) {
    src[k] = vi;
  } else {
    dst[k - N_EDGES] = vi;
    atomicAdd(&deg[vi], 1);
  }
}

__global__ __launch_bounds__(256) void k_scan1(const int* __restrict__ deg,
                                               int* __restrict__ incl,
                                               int* __restrict__ bsums) {
  __shared__ int sh[256];
  int i = blockIdx.x * 256 + threadIdx.x;
  int v = (i < N_NODES) ? deg[i] : 0;
  sh[threadIdx.x] = v;
  __syncthreads();
  for (int off = 1; off < 256; off <<= 1) {
    int t = (threadIdx.x >= (unsigned)off) ? sh[threadIdx.x - off] : 0;
    __syncthreads();
    sh[threadIdx.x] += t;
    __syncthreads();
  }
  if (i < N_NODES) incl[i] = sh[threadIdx.x];
  if (threadIdx.x == 255) bsums[blockIdx.x] = sh[255];
}

__global__ __launch_bounds__(512) void k_scan2(int* __restrict__ bsums, int nb) {
  __shared__ int sh[512];
  int t = threadIdx.x;
  sh[t] = (t < nb) ? bsums[t] : 0;
  __syncthreads();
  for (int off = 1; off < 512; off <<= 1) {
    int v = (t >= off) ? sh[t - off] : 0;
    __syncthreads();
    sh[t] += v;
    __syncthreads();
  }
  if (t < nb) bsums[t] = (t == 0) ? 0 : sh[t - 1];
}

__global__ __launch_bounds__(256) void k_scan3(const int* __restrict__ deg,
                                               const int* __restrict__ incl,
                                               const int* __restrict__ bsums,
                                               int* __restrict__ row_start,
                                               int* __restrict__ cursor,
                                               float* __restrict__ dinv) {
  int i = blockIdx.x * 256 + threadIdx.x;
  if (i >= N_NODES) return;
  int dg = deg[i];
  int rs = incl[i] - dg + bsums[blockIdx.x];
  row_start[i] = rs;
  cursor[i] = rs;
  dinv[i] = rsqrtf((float)(dg + 1));
  if (i == 0) row_start[N_NODES] = N_EDGES;
}

// counting-sort edges by dst; pack (src, weight) into uint2
__global__ __launch_bounds__(256) void k_fill(const int* __restrict__ src,
                                              const int* __restrict__ dst,
                                              const float* __restrict__ dinv,
                                              int* __restrict__ cursor,
                                              uint2* __restrict__ csr) {
  int e = blockIdx.x * 256 + threadIdx.x;
  if (e >= N_EDGES) return;
  int s = src[e], d = dst[e];
  int p = atomicAdd(&cursor[d], 1);
  csr[p] = make_uint2((unsigned)s, __float_as_uint(dinv[s] * dinv[d]));
}

__global__ __launch_bounds__(256) void k_x2bf(const float* __restrict__ x,
                                              unsigned short* __restrict__ o,
                                              int n4) {
  int i = blockIdx.x * 256 + threadIdx.x;
  if (i >= n4) return;
  float4 v = ((const float4*)x)[i];
  ushort4 r;
  r.x = f2bf(v.x); r.y = f2bf(v.y); r.z = f2bf(v.z); r.w = f2bf(v.w);
  ((ushort4*)o)[i] = r;
}

// weight transpose to bf16: W[K][N] -> Bt[Npad][K]
__global__ __launch_bounds__(256) void k_wsplit(const float* __restrict__ W,
                                                int K, int N, int Npad,
                                                unsigned short* __restrict__ Bt) {
  int idx = blockIdx.x * 256 + threadIdx.x;
  if (idx >= Npad * K) return;
  int n = idx / K, k = idx - n * K;
  float w = (n < N) ? W[(size_t)k * N + n] : 0.f;
  Bt[idx] = f2bf(w);
}

// ---------------------------------------------------------------------------
// gather aggregation, bf16 in/out, fp32 accumulate.
// Each wave handles 128 features of one node (HALVES waves per node).
// Edge loop unrolled x2 for memory-level parallelism; csr packed uint2.
// ---------------------------------------------------------------------------
template <int F, int HALVES>
__global__ __launch_bounds__(256) void k_agg(const unsigned* __restrict__ in,
                                             unsigned* __restrict__ out,
                                             const float* __restrict__ dinv,
                                             const int* __restrict__ row_start,
                                             const uint2* __restrict__ csr) {
  int wid = (blockIdx.x << 2) + (threadIdx.x >> 6);
  int lane = threadIdx.x & 63;
  int node = wid / HALVES;
  int sec = wid % HALVES;
  if (node >= N_NODES) return;
  const unsigned* base = in + sec * 64 + lane;
  float d = dinv[node];
  float d2 = d * d;
  unsigned u0 = base[(size_t)node * (F / 2)];
  float a0 = bflo(u0) * d2, a1 = bfhi(u0) * d2;
  int e = row_start[node], e1 = row_start[node + 1];
  for (; e + 2 <= e1; e += 2) {
    uint2 c0 = csr[e];
    uint2 c1 = csr[e + 1];
    unsigned r0 = base[(size_t)c0.x * (F / 2)];
    unsigned r1 = base[(size_t)c1.x * (F / 2)];
    float w0 = __uint_as_float(c0.y);
    float w1 = __uint_as_float(c1.y);
    a0 = fmaf(bflo(r0), w0, a0);
    a1 = fmaf(bfhi(r0), w0, a1);
    a0 = fmaf(bflo(r1), w1, a0);
    a1 = fmaf(bfhi(r1), w1, a1);
  }
  if (e < e1) {
    uint2 c0 = csr[e];
    unsigned r0 = base[(size_t)c0.x * (F / 2)];
    float w0 = __uint_as_float(c0.y);
    a0 = fmaf(bflo(r0), w0, a0);
    a1 = fmaf(bfhi(r0), w0, a1);
  }
  unsigned lo = f2bf(a0), hi = f2bf(a1);
  out[(size_t)node * (F / 2) + sec * 64 + lane] = lo | (hi << 16);
}

// ---------------------------------------------------------------------------
// MFMA GEMM: C[M,ldc] = A[M,K](bf16) @ B[Npad,K]^T (+bias)(+relu)
// 128x128 tile, BK=32, 4 waves 2x2, each wave 64x64 (4x4 mfma 16x16x32).
// Stores only columns < ldc (compact output for layer 3).
// ---------------------------------------------------------------------------
template <bool OUTBF>
__global__ __launch_bounds__(256) void k_gemm_mfma(const unsigned short* __restrict__ A,
                                                   int lda,
                                                   const unsigned short* __restrict__ B,
                                                   const float* __restrict__ bias,
                                                   void* __restrict__ C, int ldc,
                                                   int M, int K, int relu) {
  __shared__ alignas(16) unsigned short As[128][40];
  __shared__ alignas(16) unsigned short Bs[128][40];
  int tid = threadIdx.x;
  int lane = tid & 63, wv = tid >> 6;
  int wy = wv >> 1, wx = wv & 1;
  int row0 = blockIdx.x * 128, col0 = blockIdx.y * 128;

  f32x4 acc[4][4];
#pragma unroll
  for (int i = 0; i < 4; i++)
#pragma unroll
    for (int j = 0; j < 4; j++) acc[i][j] = 0.f;

  int sr0 = tid >> 2;
  int sc = (tid & 3) * 8;

  for (int k0 = 0; k0 < K; k0 += 32) {
#pragma unroll
    for (int it = 0; it < 2; it++) {
      int r = sr0 + it * 64;
      int gr = row0 + r;
      short8 va = 0;
      if (gr < M) va = *(const short8*)(A + (size_t)gr * lda + k0 + sc);
      *(short8*)&As[r][sc] = va;
      short8 vb = *(const short8*)(B + (size_t)(col0 + r) * K + k0 + sc);
      *(short8*)&Bs[r][sc] = vb;
    }
    __syncthreads();

    int ar = wy * 64 + (lane & 15);
    int br = wx * 64 + (lane & 15);
    int kk = (lane >> 4) * 8;
    short8 a[4], b[4];
#pragma unroll
    for (int mi = 0; mi < 4; mi++) a[mi] = *(const short8*)&As[ar + mi * 16][kk];
#pragma unroll
    for (int ni = 0; ni < 4; ni++) b[ni] = *(const short8*)&Bs[br + ni * 16][kk];
#pragma unroll
    for (int mi = 0; mi < 4; mi++)
#pragma unroll
      for (int ni = 0; ni < 4; ni++)
        acc[mi][ni] = __builtin_amdgcn_mfma_f32_16x16x32_bf16(a[mi], b[ni], acc[mi][ni], 0, 0, 0);
    __syncthreads();
  }

  int mbase = row0 + wy * 64;
  int nbase = col0 + wx * 64;
#pragma unroll
  for (int ni = 0; ni < 4; ni++) {
    int gc = nbase + ni * 16 + (lane & 15);
    if (gc >= ldc) continue;
    float bz = bias ? bias[gc] : 0.f;
#pragma unroll
    for (int mi = 0; mi < 4; mi++) {
      f32x4 v = acc[mi][ni];
#pragma unroll
      for (int r = 0; r < 4; r++) {
        int gr = mbase + mi * 16 + (lane >> 4) * 4 + r;
        if (gr < M) {
          float o = v[r] + bz;
          if (relu) o = fmaxf(o, 0.f);
          if (OUTBF) ((unsigned short*)C)[(size_t)gr * ldc + gc] = f2bf(o);
          else       ((float*)C)[(size_t)gr * ldc + gc] = o;
        }
      }
    }
  }
}

// ---------------------------------------------------------------------------
// layer-3: gather-agg over compact bf16 logits [N][64] (lane<20, 2 cls/lane)
// + bias + log_softmax, fp32 out.
// ---------------------------------------------------------------------------
__global__ __launch_bounds__(256) void k_agg40_lsm(const unsigned* __restrict__ in,  // [N][32] uints
                                                   float* __restrict__ out,
                                                   const float* __restrict__ dinv,
                                                   const int* __restrict__ row_start,
                                                   const uint2* __restrict__ csr,
                                                   const float* __restrict__ bias) {
  int node = (blockIdx.x << 2) + (threadIdx.x >> 6);
  int lane = threadIdx.x & 63;
  if (node >= N_NODES) return;
  bool act = lane < 20;
  int cl = act ? lane : 0;  // clamp inactive lanes to safe addresses
  const unsigned* base = in + cl;
  float d = dinv[node];
  float d2 = d * d;
  unsigned u0 = base[(size_t)node * 32];
  float a0 = bflo(u0) * d2, a1 = bfhi(u0) * d2;
  int e = row_start[node], e1 = row_start[node + 1];
  for (; e + 2 <= e1; e += 2) {
    uint2 c0 = csr[e];
    uint2 c1 = csr[e + 1];
    unsigned r0 = base[(size_t)c0.x * 32];
    unsigned r1 = base[(size_t)c1.x * 32];
    float w0 = __uint_as_float(c0.y);
    float w1 = __uint_as_float(c1.y);
    a0 = fmaf(bflo(r0), w0, a0);
    a1 = fmaf(bfhi(r0), w0, a1);
    a0 = fmaf(bflo(r1), w1, a0);
    a1 = fmaf(bfhi(r1), w1, a1);
  }
  if (e < e1) {
    uint2 c0 = csr[e];
    unsigned r0 = base[(size_t)c0.x * 32];
    float w0 = __uint_as_float(c0.y);
    a0 = fmaf(bflo(r0), w0, a0);
    a1 = fmaf(bfhi(r0), w0, a1);
  }
  float v0 = act ? a0 + bias[2 * lane] : -INFINITY;
  float v1 = act ? a1 + bias[2 * lane + 1] : -INFINITY;
  float m = fmaxf(v0, v1);
  for (int off = 32; off; off >>= 1) m = fmaxf(m, __shfl_down(m, off));
  m = __shfl(m, 0);
  float s = act ? expf(v0 - m) + expf(v1 - m) : 0.f;
  for (int off = 32; off; off >>= 1) s += __shfl_down(s, off);
  s = __shfl(s, 0);
  float lse = m + logf(s);
  if (act) {
    out[(size_t)node * N_CLS + 2 * lane] = v0 - lse;
    out[(size_t)node * N_CLS + 2 * lane + 1] = v1 - lse;
  }
}

// ---------------------------------------------------------------------------
extern "C" void kernel_launch(void* const* d_in, const int* in_sizes, int n_in,
                              void* d_out, int out_size, void* d_ws, size_t ws_size,
                              hipStream_t stream) {
  const float* x  = (const float*)d_in[0];
  const void*  ei = d_in[1];
  const float* W1 = (const float*)d_in[2];
  const float* b1 = (const float*)d_in[3];
  const float* W2 = (const float*)d_in[4];
  const float* b2 = (const float*)d_in[5];
  const float* W3 = (const float*)d_in[6];
  const float* b3 = (const float*)d_in[7];
  float* out = (float*)d_out;

  char* w = (char*)d_ws;
  auto alloc = [&](size_t bytes) {
    char* p = w;
    w += (bytes + 255) & ~(size_t)255;
    return p;
  };
  int*   flag      = (int*)alloc(64);
  int*   src       = (int*)alloc((size_t)N_EDGES * 4);
  int*   dst       = (int*)alloc((size_t)N_EDGES * 4);
  int*   deg       = (int*)alloc((size_t)N_NODES * 4);
  float* dinv      = (float*)alloc((size_t)N_NODES * 4);
  int*   incl      = (int*)alloc((size_t)N_NODES * 4);
  int*   cursor    = (int*)alloc((size_t)N_NODES * 4);
  int*   row_start = (int*)alloc(((size_t)N_NODES + 1) * 4);
  int*   bsums     = (int*)alloc(2048);
  uint2* csr       = (uint2*)alloc((size_t)N_EDGES * 8);
  unsigned short* Wt1 = (unsigned short*)alloc((size_t)HID * IN_DIM * 2);
  unsigned short* Wt2 = (unsigned short*)alloc((size_t)HID * HID * 2);
  unsigned short* Wt3 = (unsigned short*)alloc((size_t)128 * HID * 2);
  char* R0 = alloc((size_t)N_NODES * HID * 2);  // 51.2 MB
  char* R1 = alloc((size_t)N_NODES * HID * 2);  // 51.2 MB

  unsigned short* xb    = (unsigned short*)R0;                       // [N,128] bf16
  unsigned short* aggX  = (unsigned short*)R0 + (size_t)N_NODES * 128;
  unsigned short* h1    = (unsigned short*)R1;                       // [N,256] bf16
  unsigned short* aggH1 = (unsigned short*)R0;                       // [N,256] bf16 (over xb/aggX)
  unsigned short* h2    = (unsigned short*)R1;                       // [N,256] bf16 (over h1)
  unsigned short* C3    = (unsigned short*)R0;                       // [N,64]  bf16 (over aggH1)

  const int nb_nodes = (N_NODES + 255) / 256;
  const int nb_conv  = (2 * N_EDGES + 255) / 256;
  const int nb_edges = (N_EDGES + 255) / 256;
  const int nb_w1    = (N_NODES + 3) / 4;        // wave per node
  const int nb_w2    = (N_NODES * 2 + 3) / 4;    // wave per half-node
  const int gm       = (N_NODES + 127) / 128;

  // graph preprocessing
  k_pre0<<<nb_nodes, 256, 0, stream>>>((const unsigned int*)ei, flag, deg);
  k_convert<<<nb_conv, 256, 0, stream>>>(ei, flag, src, dst, deg);
  k_scan1<<<nb_nodes, 256, 0, stream>>>(deg, incl, bsums);
  k_scan2<<<1, 512, 0, stream>>>(bsums, nb_nodes);
  k_scan3<<<nb_nodes, 256, 0, stream>>>(deg, incl, bsums, row_start, cursor, dinv);
  k_fill<<<nb_edges, 256, 0, stream>>>(src, dst, dinv, cursor, csr);

  // input/weight prep
  k_x2bf<<<(N_NODES * IN_DIM / 4 + 255) / 256, 256, 0, stream>>>(x, xb, N_NODES * IN_DIM / 4);
  k_wsplit<<<(HID * IN_DIM + 255) / 256, 256, 0, stream>>>(W1, IN_DIM, HID, HID, Wt1);
  k_wsplit<<<(HID * HID + 255) / 256, 256, 0, stream>>>(W2, HID, HID, HID, Wt2);
  k_wsplit<<<(128 * HID + 255) / 256, 256, 0, stream>>>(W3, HID, N_CLS, 128, Wt3);

  // layer 1: agg(x) @ W1 + b1, relu
  k_agg<IN_DIM, 1><<<nb_w1, 256, 0, stream>>>((const unsigned*)xb, (unsigned*)aggX,
                                              dinv, row_start, csr);
  k_gemm_mfma<true><<<dim3(gm, HID / 128), 256, 0, stream>>>(aggX, IN_DIM, Wt1, b1,
                                                             h1, HID, N_NODES, IN_DIM, 1);
  // layer 2: agg(h1) @ W2 + b2, relu
  k_agg<HID, 2><<<nb_w2, 256, 0, stream>>>((const unsigned*)h1, (unsigned*)aggH1,
                                           dinv, row_start, csr);
  k_gemm_mfma<true><<<dim3(gm, HID / 128), 256, 0, stream>>>(aggH1, HID, Wt2, b2,
                                                             h2, HID, N_NODES, HID, 1);
  // layer 3: agg(h2 @ W3) + b3, log_softmax
  k_gemm_mfma<true><<<dim3(gm, 1), 256, 0, stream>>>(h2, HID, Wt3, nullptr,
                                                     C3, 64, N_NODES, HID, 0);
  k_agg40_lsm<<<nb_w1, 256, 0, stream>>>((const unsigned*)C3, out, dinv, row_start, csr, b3);
}